// Round 1
// baseline (3359.509 us; speedup 1.0000x reference)
//
#include <hip/hip_runtime.h>

#define N_NODES 20000
#define D_FEAT 256
#define N_SUPPORT 3
#define N_EDGES 320000
#define OUT_DIM 256

// y[s][n][c] = sum_k x[n][k] * W[s*D_FEAT + k][c]
// grid: (N_NODES/16, N_SUPPORT), block: 256 threads (thread = output col c)
__global__ void gemm_xw(const float* __restrict__ x, const float* __restrict__ W,
                        float* __restrict__ y) {
    __shared__ float xs[16][D_FEAT];
    const int s = blockIdx.y;
    const int row0 = blockIdx.x * 16;
    const int tid = threadIdx.x;

    // stage 16 rows of x into LDS (16*256 floats, float4 loads)
    for (int i = tid; i < 16 * (D_FEAT / 4); i += 256) {
        int r = i / (D_FEAT / 4);
        int kk = i % (D_FEAT / 4);
        ((float4*)xs[r])[kk] = ((const float4*)(x + (size_t)(row0 + r) * D_FEAT))[kk];
    }
    __syncthreads();

    const int c = tid;
    float acc[16];
#pragma unroll
    for (int r = 0; r < 16; ++r) acc[r] = 0.f;

    const float* Wp = W + (size_t)s * D_FEAT * OUT_DIM + c;
    for (int k = 0; k < D_FEAT; k += 4) {
        const float w0 = Wp[(size_t)(k + 0) * OUT_DIM];
        const float w1 = Wp[(size_t)(k + 1) * OUT_DIM];
        const float w2 = Wp[(size_t)(k + 2) * OUT_DIM];
        const float w3 = Wp[(size_t)(k + 3) * OUT_DIM];
#pragma unroll
        for (int r = 0; r < 16; ++r) {
            float4 xv = *(const float4*)&xs[r][k];
            acc[r] += xv.x * w0 + xv.y * w1 + xv.z * w2 + xv.w * w3;
        }
    }

    float* yp = y + ((size_t)s * N_NODES + row0) * OUT_DIM + c;
#pragma unroll
    for (int r = 0; r < 16; ++r) yp[(size_t)r * OUT_DIM] = acc[r];
}

// out[dst[e]] += w[e] * y[s][src[e]]   -- one wave (64 lanes) per edge
__global__ void scatter_edges(const float* __restrict__ y, const int* __restrict__ src,
                              const int* __restrict__ dst, const float* __restrict__ w,
                              float* __restrict__ out) {
    const int gwave = (int)((blockIdx.x * (size_t)blockDim.x + threadIdx.x) >> 6);
    const int lane = threadIdx.x & 63;
    const int total = N_SUPPORT * N_EDGES;
    if (gwave >= total) return;

    const int s = gwave / N_EDGES;
    const int e = gwave - s * N_EDGES;
    const size_t idx = (size_t)s * N_EDGES + e;
    const int sn = src[idx];
    const int dn = dst[idx];
    const float ww = w[idx];

    const float4* yp = (const float4*)(y + ((size_t)s * N_NODES + sn) * OUT_DIM);
    float* op = out + (size_t)dn * OUT_DIM;

    float4 v = yp[lane];
    atomicAdd(op + lane * 4 + 0, v.x * ww);
    atomicAdd(op + lane * 4 + 1, v.y * ww);
    atomicAdd(op + lane * 4 + 2, v.z * ww);
    atomicAdd(op + lane * 4 + 3, v.w * ww);
}

extern "C" void kernel_launch(void* const* d_in, const int* in_sizes, int n_in,
                              void* d_out, int out_size, void* d_ws, size_t ws_size,
                              hipStream_t stream) {
    const float* x        = (const float*)d_in[0];
    const int*   edge_src = (const int*)d_in[1];
    const int*   edge_dst = (const int*)d_in[2];
    const float* edge_w   = (const float*)d_in[3];
    const float* W        = (const float*)d_in[4];
    float* out = (float*)d_out;

    float* y = (float*)d_ws;  // [N_SUPPORT][N_NODES][OUT_DIM] fp32 = 61.44 MB

    // zero the output (harness poisons it; scatter accumulates with atomics)
    hipMemsetAsync(out, 0, (size_t)out_size * sizeof(float), stream);

    // y_s = x @ W_s
    dim3 ggrid(N_NODES / 16, N_SUPPORT);
    gemm_xw<<<ggrid, 256, 0, stream>>>(x, W, y);

    // out[dst] += w * y_s[src]
    const int total_waves = N_SUPPORT * N_EDGES;       // 960000 edges
    const int waves_per_block = 4;                     // 256 threads
    const int nblocks = (total_waves + waves_per_block - 1) / waves_per_block;
    scatter_edges<<<nblocks, 256, 0, stream>>>(y, edge_src, edge_dst, edge_w, out);
}

// Round 2
// 459.741 us; speedup vs baseline: 7.3074x; 7.3074x over previous
//
#include <hip/hip_runtime.h>

#define N_NODES 20000
#define D_FEAT 256
#define N_SUPPORT 3
#define N_EDGES 320000
#define OUT_DIM 256
#define TOTAL_E (N_SUPPORT * N_EDGES)

// ---------------- GEMM: y[s][n][c] = sum_k x[n][k] * W[s*D_FEAT+k][c] ----------------
__global__ void gemm_xw(const float* __restrict__ x, const float* __restrict__ W,
                        float* __restrict__ y) {
    __shared__ float xs[16][D_FEAT];
    const int s = blockIdx.y;
    const int row0 = blockIdx.x * 16;
    const int tid = threadIdx.x;

    for (int i = tid; i < 16 * (D_FEAT / 4); i += 256) {
        int r = i / (D_FEAT / 4);
        int kk = i % (D_FEAT / 4);
        ((float4*)xs[r])[kk] = ((const float4*)(x + (size_t)(row0 + r) * D_FEAT))[kk];
    }
    __syncthreads();

    const int c = tid;
    float acc[16];
#pragma unroll
    for (int r = 0; r < 16; ++r) acc[r] = 0.f;

    const float* Wp = W + (size_t)s * D_FEAT * OUT_DIM + c;
    for (int k = 0; k < D_FEAT; k += 4) {
        const float w0 = Wp[(size_t)(k + 0) * OUT_DIM];
        const float w1 = Wp[(size_t)(k + 1) * OUT_DIM];
        const float w2 = Wp[(size_t)(k + 2) * OUT_DIM];
        const float w3 = Wp[(size_t)(k + 3) * OUT_DIM];
#pragma unroll
        for (int r = 0; r < 16; ++r) {
            float4 xv = *(const float4*)&xs[r][k];
            acc[r] += xv.x * w0 + xv.y * w1 + xv.z * w2 + xv.w * w3;
        }
    }

    float* yp = y + ((size_t)s * N_NODES + row0) * OUT_DIM + c;
#pragma unroll
    for (int r = 0; r < 16; ++r) yp[(size_t)r * OUT_DIM] = acc[r];
}

// ---------------- CSR build: count -> scan -> fill ----------------
__global__ void count_edges(const int* __restrict__ dst, int* __restrict__ counts) {
    const int i = blockIdx.x * blockDim.x + threadIdx.x;
    if (i < TOTAL_E) atomicAdd(&counts[dst[i]], 1);
}

__global__ void scan_offsets(const int* __restrict__ counts, int* __restrict__ offsets) {
    __shared__ int partials[256];
    const int tid = threadIdx.x;
    const int CH = (N_NODES + 255) / 256;  // 79
    const int base = tid * CH;

    int lsum = 0;
    for (int i = 0; i < CH; ++i) {
        int idx = base + i;
        if (idx < N_NODES) lsum += counts[idx];
    }
    partials[tid] = lsum;
    __syncthreads();
    for (int d = 1; d < 256; d <<= 1) {
        int v = (tid >= d) ? partials[tid - d] : 0;
        __syncthreads();
        partials[tid] += v;
        __syncthreads();
    }
    int run = (tid == 0) ? 0 : partials[tid - 1];
    for (int i = 0; i < CH; ++i) {
        int idx = base + i;
        if (idx < N_NODES) {
            offsets[idx] = run;
            run += counts[idx];
        }
    }
    if (tid == 255) offsets[N_NODES] = run;
}

__global__ void fill_edges(const int* __restrict__ src, const int* __restrict__ dst,
                           const float* __restrict__ w, const int* __restrict__ offsets,
                           int* __restrict__ cursor, int* __restrict__ ekey,
                           float* __restrict__ ew) {
    const int i = blockIdx.x * blockDim.x + threadIdx.x;
    if (i >= TOTAL_E) return;
    const int d = dst[i];
    const int pos = offsets[d] + atomicAdd(&cursor[d], 1);
    const int s = i / N_EDGES;
    ekey[pos] = s * N_NODES + src[i];
    ew[pos] = w[i];
}

// ---------------- gather: one wave per destination node, no atomics ----------------
__global__ void gather_out(const float* __restrict__ y, const int* __restrict__ offsets,
                           const int* __restrict__ ekey, const float* __restrict__ ew,
                           float* __restrict__ out) {
    const int wid = (int)((blockIdx.x * (size_t)blockDim.x + threadIdx.x) >> 6);
    const int lane = threadIdx.x & 63;
    if (wid >= N_NODES) return;

    const int e0 = offsets[wid];
    const int e1 = offsets[wid + 1];

    float4 acc = {0.f, 0.f, 0.f, 0.f};
    for (int e = e0; e < e1; ++e) {
        const int g = ekey[e];
        const float wv = ew[e];
        float4 v = ((const float4*)(y + (size_t)g * OUT_DIM))[lane];
        acc.x += wv * v.x;
        acc.y += wv * v.y;
        acc.z += wv * v.z;
        acc.w += wv * v.w;
    }
    ((float4*)(out + (size_t)wid * OUT_DIM))[lane] = acc;
}

extern "C" void kernel_launch(void* const* d_in, const int* in_sizes, int n_in,
                              void* d_out, int out_size, void* d_ws, size_t ws_size,
                              hipStream_t stream) {
    const float* x        = (const float*)d_in[0];
    const int*   edge_src = (const int*)d_in[1];
    const int*   edge_dst = (const int*)d_in[2];
    const float* edge_w   = (const float*)d_in[3];
    const float* W        = (const float*)d_in[4];
    float* out = (float*)d_out;

    char* ws = (char*)d_ws;
    float* y       = (float*)(ws);                    // 61,440,000 B
    int*   counts  = (int*)(ws + 61440000);           //     80,000 B
    int*   cursor  = (int*)(ws + 61520000);           //     80,000 B
    int*   offsets = (int*)(ws + 61600000);           //     80,064 B (20001 ints)
    int*   ekey    = (int*)(ws + 61680064);           //  3,840,000 B
    float* ew      = (float*)(ws + 65520064);         //  3,840,000 B
    // total: 69,360,064 B

    // zero counts + cursor (contiguous 160,000 B)
    hipMemsetAsync(counts, 0, 160000, stream);

    // y_s = x @ W_s
    dim3 ggrid(N_NODES / 16, N_SUPPORT);
    gemm_xw<<<ggrid, 256, 0, stream>>>(x, W, y);

    // CSR build keyed by destination
    const int nb_e = (TOTAL_E + 255) / 256;
    count_edges<<<nb_e, 256, 0, stream>>>(edge_dst, counts);
    scan_offsets<<<1, 256, 0, stream>>>(counts, offsets);
    fill_edges<<<nb_e, 256, 0, stream>>>(edge_src, edge_dst, edge_w, offsets, cursor, ekey, ew);

    // out[n] = sum over incident edges of w * y[gsrc]
    const int nb_g = (N_NODES + 3) / 4;  // 4 waves per 256-thread block
    gather_out<<<nb_g, 256, 0, stream>>>(y, offsets, ekey, ew, out);
}

// Round 3
// 328.149 us; speedup vs baseline: 10.2378x; 1.4010x over previous
//
#include <hip/hip_runtime.h>

#define N_NODES 20000
#define D_FEAT 256
#define N_SUPPORT 3
#define N_EDGES 320000
#define OUT_DIM 256
#define TOTAL_E (N_SUPPORT * N_EDGES)
#define M_TILES (N_NODES / 16)  // 1250

typedef __attribute__((ext_vector_type(8))) short short8;
typedef __attribute__((ext_vector_type(4))) float f32x4;

__device__ inline unsigned short f2bf(float f) {
    unsigned int u = __float_as_uint(f);
    u += 0x7fff + ((u >> 16) & 1);  // round-to-nearest-even
    return (unsigned short)(u >> 16);
}
__device__ inline float bf2f(unsigned short u) {
    return __uint_as_float(((unsigned int)u) << 16);
}

// x (fp32 [N][256]) -> xb (bf16 [N][256]); 4 elems/thread
__global__ void convert_x(const float* __restrict__ x, unsigned short* __restrict__ xb) {
    int i = blockIdx.x * blockDim.x + threadIdx.x;
    if ((size_t)i * 4 >= (size_t)N_NODES * D_FEAT) return;
    float4 v = ((const float4*)x)[i];
    ushort4 o;
    o.x = f2bf(v.x); o.y = f2bf(v.y); o.z = f2bf(v.z); o.w = f2bf(v.w);
    ((ushort4*)xb)[i] = o;
}

// W (fp32 [S*256][256]) -> wt (bf16 [S][n=256][k=256]) transposed
__global__ void convert_w(const float* __restrict__ W, unsigned short* __restrict__ wt) {
    const int row = blockIdx.x;      // s*256 + k
    const int n = threadIdx.x;       // 0..255
    const int s = row >> 8;
    const int k = row & 255;
    float v = W[(size_t)row * OUT_DIM + n];
    wt[((size_t)s * OUT_DIM + n) * D_FEAT + k] = f2bf(v);
}

// y_s = x @ W_s via MFMA; yb bf16 [S][N_NODES][256]
// grid: (ceil(1250/4), 3), block 256 (4 waves, each wave = one 16-row M-tile x all 256 cols)
__global__ void __launch_bounds__(256) gemm_mfma(const unsigned short* __restrict__ xb,
                                                 const unsigned short* __restrict__ wt,
                                                 unsigned short* __restrict__ yb) {
    const int s = blockIdx.y;
    const int wid = threadIdx.x >> 6;
    const int lane = threadIdx.x & 63;
    const int tile_m = blockIdx.x * 4 + wid;
    if (tile_m >= M_TILES) return;
    const int r0 = tile_m * 16;
    const int cit = lane & 15;          // A-row / B-col / D-col within tile
    const int kgrp = (lane >> 4) * 8;   // k-offset of this lane's 8 contiguous elems

    const short* ap = (const short*)xb + (size_t)(r0 + cit) * D_FEAT + kgrp;
    const short* bp = (const short*)wt + (size_t)s * D_FEAT * OUT_DIM + (size_t)cit * D_FEAT + kgrp;

    f32x4 acc[16];
#pragma unroll
    for (int nt = 0; nt < 16; ++nt) acc[nt] = (f32x4){0.f, 0.f, 0.f, 0.f};

#pragma unroll
    for (int kk = 0; kk < 8; ++kk) {
        short8 a = *(const short8*)(ap + kk * 32);
#pragma unroll
        for (int nt = 0; nt < 16; ++nt) {
            short8 b = *(const short8*)(bp + (size_t)nt * 16 * D_FEAT + kk * 32);
            acc[nt] = __builtin_amdgcn_mfma_f32_16x16x32_bf16(a, b, acc[nt], 0, 0, 0);
        }
    }

    unsigned short* yp = (unsigned short*)yb + ((size_t)s * N_NODES + r0) * OUT_DIM;
    const int rbase = (lane >> 4) * 4;
#pragma unroll
    for (int nt = 0; nt < 16; ++nt) {
#pragma unroll
        for (int r = 0; r < 4; ++r) {
            yp[(size_t)(rbase + r) * OUT_DIM + nt * 16 + cit] = f2bf(acc[nt][r]);
        }
    }
}

// ---------------- CSR build ----------------
__global__ void count_edges(const int* __restrict__ dst, int* __restrict__ counts) {
    const int i = blockIdx.x * blockDim.x + threadIdx.x;
    if (i < TOTAL_E) atomicAdd(&counts[dst[i]], 1);
}

__global__ void scan_offsets(const int* __restrict__ counts, int* __restrict__ offsets) {
    __shared__ int partials[256];
    const int tid = threadIdx.x;
    const int CH = (N_NODES + 255) / 256;  // 79
    const int base = tid * CH;

    int lsum = 0;
    for (int i = 0; i < CH; ++i) {
        int idx = base + i;
        if (idx < N_NODES) lsum += counts[idx];
    }
    partials[tid] = lsum;
    __syncthreads();
    for (int d = 1; d < 256; d <<= 1) {
        int v = (tid >= d) ? partials[tid - d] : 0;
        __syncthreads();
        partials[tid] += v;
        __syncthreads();
    }
    int run = (tid == 0) ? 0 : partials[tid - 1];
    for (int i = 0; i < CH; ++i) {
        int idx = base + i;
        if (idx < N_NODES) {
            offsets[idx] = run;
            run += counts[idx];
        }
    }
    if (tid == 255) offsets[N_NODES] = run;
}

__global__ void fill_edges(const int* __restrict__ src, const int* __restrict__ dst,
                           const float* __restrict__ w, const int* __restrict__ offsets,
                           int* __restrict__ cursor, int2* __restrict__ epack) {
    const int i = blockIdx.x * blockDim.x + threadIdx.x;
    if (i >= TOTAL_E) return;
    const int d = dst[i];
    const int pos = offsets[d] + atomicAdd(&cursor[d], 1);
    const int s = i / N_EDGES;
    int2 kp;
    kp.x = s * N_NODES + src[i];
    kp.y = __float_as_int(w[i]);
    epack[pos] = kp;
}

// ---------------- gather: one wave per destination node ----------------
__global__ void gather_out(const unsigned short* __restrict__ yb, const int* __restrict__ offsets,
                           const int2* __restrict__ epack, float* __restrict__ out) {
    const int wid = (int)((blockIdx.x * (size_t)blockDim.x + threadIdx.x) >> 6);
    const int lane = threadIdx.x & 63;
    if (wid >= N_NODES) return;

    const int e0 = offsets[wid];
    const int e1 = offsets[wid + 1];

    float4 acc = {0.f, 0.f, 0.f, 0.f};
    for (int e = e0; e < e1; ++e) {
        const int2 kp = epack[e];
        const float wv = __int_as_float(kp.y);
        ushort4 v = ((const ushort4*)(yb + (size_t)kp.x * OUT_DIM))[lane];
        acc.x += wv * bf2f(v.x);
        acc.y += wv * bf2f(v.y);
        acc.z += wv * bf2f(v.z);
        acc.w += wv * bf2f(v.w);
    }
    ((float4*)(out + (size_t)wid * OUT_DIM))[lane] = acc;
}

extern "C" void kernel_launch(void* const* d_in, const int* in_sizes, int n_in,
                              void* d_out, int out_size, void* d_ws, size_t ws_size,
                              hipStream_t stream) {
    const float* x        = (const float*)d_in[0];
    const int*   edge_src = (const int*)d_in[1];
    const int*   edge_dst = (const int*)d_in[2];
    const float* edge_w   = (const float*)d_in[3];
    const float* W        = (const float*)d_in[4];
    float* out = (float*)d_out;

    char* ws = (char*)d_ws;
    unsigned short* yb   = (unsigned short*)(ws);               // 30,720,000 B
    unsigned short* xb   = (unsigned short*)(ws + 30720000);    // 10,240,000 B
    unsigned short* wt   = (unsigned short*)(ws + 40960000);    //    393,216 B
    int*   counts  = (int*)(ws + 41353216);                     //     80,000 B
    int*   cursor  = (int*)(ws + 41433216);                     //     80,000 B
    int*   offsets = (int*)(ws + 41513216);                     //     80,064 B
    int2*  epack   = (int2*)(ws + 41593280);                    //  7,680,000 B
    // total: 49,273,280 B

    hipMemsetAsync(counts, 0, 160000, stream);  // counts + cursor (contiguous)

    convert_x<<<(N_NODES * D_FEAT / 4 + 255) / 256, 256, 0, stream>>>(x, xb);
    convert_w<<<N_SUPPORT * D_FEAT, 256, 0, stream>>>(W, wt);

    dim3 ggrid((M_TILES + 3) / 4, N_SUPPORT);
    gemm_mfma<<<ggrid, 256, 0, stream>>>(xb, wt, yb);

    const int nb_e = (TOTAL_E + 255) / 256;
    count_edges<<<nb_e, 256, 0, stream>>>(edge_dst, counts);
    scan_offsets<<<1, 256, 0, stream>>>(counts, offsets);
    fill_edges<<<nb_e, 256, 0, stream>>>(edge_src, edge_dst, edge_w, offsets, cursor, epack);

    const int nb_g = (N_NODES + 3) / 4;
    gather_out<<<nb_g, 256, 0, stream>>>(yb, offsets, epack, out);
}

// Round 4
// 272.054 us; speedup vs baseline: 12.3487x; 1.2062x over previous
//
#include <hip/hip_runtime.h>

#define N_NODES 20000
#define D_FEAT 256
#define N_SUPPORT 3
#define N_EDGES 320000
#define OUT_DIM 256
#define TOTAL_E (N_SUPPORT * N_EDGES)
#define M_TILES (N_NODES / 16)      // 1250
#define M_PAIRS (M_TILES / 2)       // 625

typedef __attribute__((ext_vector_type(8))) short short8;
typedef __attribute__((ext_vector_type(8))) unsigned short ushort8;
typedef __attribute__((ext_vector_type(4))) float f32x4;

__device__ inline unsigned short f2bf(float f) {
    unsigned int u = __float_as_uint(f);
    u += 0x7fff + ((u >> 16) & 1);  // round-to-nearest-even
    return (unsigned short)(u >> 16);
}
__device__ inline float bf2f(unsigned short u) {
    return __uint_as_float(((unsigned int)u) << 16);
}

// x (fp32 [N][256]) -> xb (bf16 [N][256]); 4 elems/thread
__global__ void convert_x(const float* __restrict__ x, unsigned short* __restrict__ xb) {
    int i = blockIdx.x * blockDim.x + threadIdx.x;
    if ((size_t)i * 4 >= (size_t)N_NODES * D_FEAT) return;
    float4 v = ((const float4*)x)[i];
    ushort4 o;
    o.x = f2bf(v.x); o.y = f2bf(v.y); o.z = f2bf(v.z); o.w = f2bf(v.w);
    ((ushort4*)xb)[i] = o;
}

// W (fp32 [S*256][256]) -> wt (bf16 [S][n=256][k=256]) transposed
__global__ void convert_w(const float* __restrict__ W, unsigned short* __restrict__ wt) {
    const int row = blockIdx.x;      // s*256 + k
    const int n = threadIdx.x;       // 0..255
    const int s = row >> 8;
    const int k = row & 255;
    float v = W[(size_t)row * OUT_DIM + n];
    wt[((size_t)s * OUT_DIM + n) * D_FEAT + k] = f2bf(v);
}

// y_s = x @ W_s via MFMA. yb stored PERMUTED within each row:
//   stored position p = cit*16 + nt  holds true column c = nt*16 + cit
//   (i.e. c = ((p&15)<<4) | (p>>4))
// Each wave: 2 M-tiles (32 rows) x 256 cols. grid: (ceil(625/4), 3), block 256.
__global__ void __launch_bounds__(256) gemm_mfma(const unsigned short* __restrict__ xb,
                                                 const unsigned short* __restrict__ wt,
                                                 unsigned short* __restrict__ yb) {
    const int s = blockIdx.y;
    const int wid = threadIdx.x >> 6;
    const int lane = threadIdx.x & 63;
    const int pair = blockIdx.x * 4 + wid;
    if (pair >= M_PAIRS) return;
    const int r0 = pair * 32;
    const int cit = lane & 15;
    const int kgrp = (lane >> 4) * 8;

    const short* a0p = (const short*)xb + (size_t)(r0 + cit) * D_FEAT + kgrp;
    const short* a1p = a0p + (size_t)16 * D_FEAT;
    const short* bp  = (const short*)wt + (size_t)s * D_FEAT * OUT_DIM + (size_t)cit * D_FEAT + kgrp;

    f32x4 acc0[16], acc1[16];
#pragma unroll
    for (int nt = 0; nt < 16; ++nt) {
        acc0[nt] = (f32x4){0.f, 0.f, 0.f, 0.f};
        acc1[nt] = (f32x4){0.f, 0.f, 0.f, 0.f};
    }

#pragma unroll
    for (int kk = 0; kk < 8; ++kk) {
        short8 a0 = *(const short8*)(a0p + kk * 32);
        short8 a1 = *(const short8*)(a1p + kk * 32);
#pragma unroll
        for (int nt = 0; nt < 16; ++nt) {
            short8 b = *(const short8*)(bp + (size_t)nt * 16 * D_FEAT + kk * 32);
            acc0[nt] = __builtin_amdgcn_mfma_f32_16x16x32_bf16(a0, b, acc0[nt], 0, 0, 0);
            acc1[nt] = __builtin_amdgcn_mfma_f32_16x16x32_bf16(a1, b, acc1[nt], 0, 0, 0);
        }
    }

    // permuted store: row rr, positions p = cit*16 + nt (contiguous in nt)
    unsigned short* yp = (unsigned short*)yb + ((size_t)s * N_NODES + r0) * OUT_DIM;
    const int rbase = (lane >> 4) * 4;
#pragma unroll
    for (int r = 0; r < 4; ++r) {
        ushort8 o0a, o0b, o1a, o1b;
#pragma unroll
        for (int j = 0; j < 8; ++j) {
            o0a[j] = f2bf(acc0[j][r]);
            o0b[j] = f2bf(acc0[8 + j][r]);
            o1a[j] = f2bf(acc1[j][r]);
            o1b[j] = f2bf(acc1[8 + j][r]);
        }
        unsigned short* row0 = yp + (size_t)(rbase + r) * OUT_DIM + cit * 16;
        unsigned short* row1 = row0 + (size_t)16 * OUT_DIM;
        *(ushort8*)(row0) = o0a;
        *(ushort8*)(row0 + 8) = o0b;
        *(ushort8*)(row1) = o1a;
        *(ushort8*)(row1 + 8) = o1b;
    }
}

// ---------------- CSR build ----------------
__global__ void count_edges(const int* __restrict__ dst, int* __restrict__ counts) {
    const int i = blockIdx.x * blockDim.x + threadIdx.x;
    if (i < TOTAL_E) atomicAdd(&counts[dst[i]], 1);
}

__global__ void scan_offsets(const int* __restrict__ counts, int* __restrict__ offsets) {
    __shared__ int partials[256];
    const int tid = threadIdx.x;
    const int CH = (N_NODES + 255) / 256;  // 79
    const int base = tid * CH;

    int lsum = 0;
    for (int i = 0; i < CH; ++i) {
        int idx = base + i;
        if (idx < N_NODES) lsum += counts[idx];
    }
    partials[tid] = lsum;
    __syncthreads();
    for (int d = 1; d < 256; d <<= 1) {
        int v = (tid >= d) ? partials[tid - d] : 0;
        __syncthreads();
        partials[tid] += v;
        __syncthreads();
    }
    int run = (tid == 0) ? 0 : partials[tid - 1];
    for (int i = 0; i < CH; ++i) {
        int idx = base + i;
        if (idx < N_NODES) {
            offsets[idx] = run;
            run += counts[idx];
        }
    }
    if (tid == 255) offsets[N_NODES] = run;
}

__global__ void fill_edges(const int* __restrict__ src, const int* __restrict__ dst,
                           const float* __restrict__ w, const int* __restrict__ offsets,
                           int* __restrict__ cursor, int2* __restrict__ epack) {
    const int i = blockIdx.x * blockDim.x + threadIdx.x;
    if (i >= TOTAL_E) return;
    const int d = dst[i];
    const int pos = offsets[d] + atomicAdd(&cursor[d], 1);
    const int s = i / N_EDGES;
    int2 kp;
    kp.x = s * N_NODES + src[i];
    kp.y = __float_as_int(w[i]);
    epack[pos] = kp;
}

// ---------------- gather: one wave per node; two 32-lane halves, 16B loads ----------------
__global__ void gather_out(const unsigned short* __restrict__ yb, const int* __restrict__ offsets,
                           const int2* __restrict__ epack, float* __restrict__ out) {
    const int wid = (int)((blockIdx.x * (size_t)blockDim.x + threadIdx.x) >> 6);
    const int lane = threadIdx.x & 63;
    if (wid >= N_NODES) return;
    const int half = lane >> 5;     // 0: even edges, 1: odd edges
    const int l32 = lane & 31;      // covers permuted positions p = l32*8 .. l32*8+7

    const int e0 = offsets[wid];
    const int e1 = offsets[wid + 1];

    float acc[8];
#pragma unroll
    for (int j = 0; j < 8; ++j) acc[j] = 0.f;

    int e = e0 + half;
    for (; e + 2 < e1; e += 4) {
        const int2 k1 = epack[e];
        const int2 k2 = epack[e + 2];
        ushort8 v1 = ((const ushort8*)(yb + (size_t)k1.x * OUT_DIM))[l32];
        ushort8 v2 = ((const ushort8*)(yb + (size_t)k2.x * OUT_DIM))[l32];
        const float w1 = __int_as_float(k1.y);
        const float w2 = __int_as_float(k2.y);
#pragma unroll
        for (int j = 0; j < 8; ++j) acc[j] += w1 * bf2f(v1[j]);
#pragma unroll
        for (int j = 0; j < 8; ++j) acc[j] += w2 * bf2f(v2[j]);
    }
    if (e < e1) {
        const int2 k1 = epack[e];
        ushort8 v1 = ((const ushort8*)(yb + (size_t)k1.x * OUT_DIM))[l32];
        const float w1 = __int_as_float(k1.y);
#pragma unroll
        for (int j = 0; j < 8; ++j) acc[j] += w1 * bf2f(v1[j]);
    }

    // combine halves
#pragma unroll
    for (int j = 0; j < 8; ++j) acc[j] += __shfl_xor(acc[j], 32, 64);

    // un-permute and store: position p = l32*8 + j  ->  col = ((p&15)<<4) | (p>>4)
    if (lane < 32) {
        float* op = out + (size_t)wid * OUT_DIM;
#pragma unroll
        for (int j = 0; j < 8; ++j) {
            const int p = l32 * 8 + j;
            const int c = ((p & 15) << 4) | (p >> 4);
            op[c] = acc[j];
        }
    }
}

extern "C" void kernel_launch(void* const* d_in, const int* in_sizes, int n_in,
                              void* d_out, int out_size, void* d_ws, size_t ws_size,
                              hipStream_t stream) {
    const float* x        = (const float*)d_in[0];
    const int*   edge_src = (const int*)d_in[1];
    const int*   edge_dst = (const int*)d_in[2];
    const float* edge_w   = (const float*)d_in[3];
    const float* W        = (const float*)d_in[4];
    float* out = (float*)d_out;

    char* ws = (char*)d_ws;
    unsigned short* yb   = (unsigned short*)(ws);               // 30,720,000 B
    unsigned short* xb   = (unsigned short*)(ws + 30720000);    // 10,240,000 B
    unsigned short* wt   = (unsigned short*)(ws + 40960000);    //    393,216 B
    int*   counts  = (int*)(ws + 41353216);                     //     80,000 B
    int*   cursor  = (int*)(ws + 41433216);                     //     80,000 B
    int*   offsets = (int*)(ws + 41513216);                     //     80,064 B
    int2*  epack   = (int2*)(ws + 41593280);                    //  7,680,000 B

    hipMemsetAsync(counts, 0, 160000, stream);  // counts + cursor (contiguous)

    convert_x<<<(N_NODES * D_FEAT / 4 + 255) / 256, 256, 0, stream>>>(x, xb);
    convert_w<<<N_SUPPORT * D_FEAT, 256, 0, stream>>>(W, wt);

    dim3 ggrid((M_PAIRS + 3) / 4, N_SUPPORT);
    gemm_mfma<<<ggrid, 256, 0, stream>>>(xb, wt, yb);

    const int nb_e = (TOTAL_E + 255) / 256;
    count_edges<<<nb_e, 256, 0, stream>>>(edge_dst, counts);
    scan_offsets<<<1, 256, 0, stream>>>(counts, offsets);
    fill_edges<<<nb_e, 256, 0, stream>>>(edge_src, edge_dst, edge_w, offsets, cursor, epack);

    const int nb_g = (N_NODES + 3) / 4;
    gather_out<<<nb_g, 256, 0, stream>>>(yb, offsets, epack, out);
}

// Round 5
// 270.245 us; speedup vs baseline: 12.4314x; 1.0067x over previous
//
#include <hip/hip_runtime.h>

#define N_NODES 20000
#define D_FEAT 256
#define N_SUPPORT 3
#define N_EDGES 320000
#define OUT_DIM 256
#define TOTAL_E (N_SUPPORT * N_EDGES)
#define M_TILES (N_NODES / 16)      // 1250
#define M_PAIRS (M_TILES / 2)       // 625

typedef __attribute__((ext_vector_type(8))) short short8;
typedef __attribute__((ext_vector_type(8))) unsigned short ushort8;
typedef __attribute__((ext_vector_type(4))) float f32x4;

__device__ inline unsigned short f2bf(float f) {
    unsigned int u = __float_as_uint(f);
    u += 0x7fff + ((u >> 16) & 1);  // round-to-nearest-even
    return (unsigned short)(u >> 16);
}
__device__ inline float bf2f(unsigned short u) {
    return __uint_as_float(((unsigned int)u) << 16);
}

// x (fp32 [N][256]) -> xb (bf16 [N][256]); 4 elems/thread
__global__ void convert_x(const float* __restrict__ x, unsigned short* __restrict__ xb) {
    int i = blockIdx.x * blockDim.x + threadIdx.x;
    if ((size_t)i * 4 >= (size_t)N_NODES * D_FEAT) return;
    float4 v = ((const float4*)x)[i];
    ushort4 o;
    o.x = f2bf(v.x); o.y = f2bf(v.y); o.z = f2bf(v.z); o.w = f2bf(v.w);
    ((ushort4*)xb)[i] = o;
}

// W (fp32 [S*256][256]) -> wt (bf16 [S][n=256][k=256]) transposed
__global__ void convert_w(const float* __restrict__ W, unsigned short* __restrict__ wt) {
    const int row = blockIdx.x;      // s*256 + k
    const int n = threadIdx.x;       // 0..255
    const int s = row >> 8;
    const int k = row & 255;
    float v = W[(size_t)row * OUT_DIM + n];
    wt[((size_t)s * OUT_DIM + n) * D_FEAT + k] = f2bf(v);
}

// y_s = x @ W_s via MFMA. yb stored PERMUTED within each row:
//   stored position p = cit*16 + nt  holds true column c = nt*16 + cit
// Each wave: 2 M-tiles (32 rows) x 8 N-tiles (128 cols).
// grid: (ceil(625/4), 3, 2), block 256.
__global__ void __launch_bounds__(256) gemm_mfma(const unsigned short* __restrict__ xb,
                                                 const unsigned short* __restrict__ wt,
                                                 unsigned short* __restrict__ yb) {
    const int s = blockIdx.y;
    const int nh = blockIdx.z;          // 0/1: which half of the 16 N-tiles
    const int wid = threadIdx.x >> 6;
    const int lane = threadIdx.x & 63;
    const int pair = blockIdx.x * 4 + wid;
    if (pair >= M_PAIRS) return;
    const int r0 = pair * 32;
    const int cit = lane & 15;
    const int kgrp = (lane >> 4) * 8;

    const short* a0p = (const short*)xb + (size_t)(r0 + cit) * D_FEAT + kgrp;
    const short* a1p = a0p + (size_t)16 * D_FEAT;
    const short* bp  = (const short*)wt + (size_t)s * D_FEAT * OUT_DIM
                     + (size_t)(nh * 8) * 16 * D_FEAT + (size_t)cit * D_FEAT + kgrp;

    f32x4 acc0[8], acc1[8];
#pragma unroll
    for (int nt = 0; nt < 8; ++nt) {
        acc0[nt] = (f32x4){0.f, 0.f, 0.f, 0.f};
        acc1[nt] = (f32x4){0.f, 0.f, 0.f, 0.f};
    }

#pragma unroll
    for (int kk = 0; kk < 8; ++kk) {
        short8 a0 = *(const short8*)(a0p + kk * 32);
        short8 a1 = *(const short8*)(a1p + kk * 32);
#pragma unroll
        for (int nt = 0; nt < 8; ++nt) {
            short8 b = *(const short8*)(bp + (size_t)nt * 16 * D_FEAT + kk * 32);
            acc0[nt] = __builtin_amdgcn_mfma_f32_16x16x32_bf16(a0, b, acc0[nt], 0, 0, 0);
            acc1[nt] = __builtin_amdgcn_mfma_f32_16x16x32_bf16(a1, b, acc1[nt], 0, 0, 0);
        }
    }

    // permuted store: row rr, positions p = cit*16 + (nh*8 + j), contiguous 8 ushorts
    unsigned short* yp = (unsigned short*)yb + ((size_t)s * N_NODES + r0) * OUT_DIM;
    const int rbase = (lane >> 4) * 4;
#pragma unroll
    for (int r = 0; r < 4; ++r) {
        ushort8 o0, o1;
#pragma unroll
        for (int j = 0; j < 8; ++j) {
            o0[j] = f2bf(acc0[j][r]);
            o1[j] = f2bf(acc1[j][r]);
        }
        unsigned short* row0 = yp + (size_t)(rbase + r) * OUT_DIM + cit * 16 + nh * 8;
        unsigned short* row1 = row0 + (size_t)16 * OUT_DIM;
        *(ushort8*)(row0) = o0;
        *(ushort8*)(row1) = o1;
    }
}

// ---------------- CSR build ----------------
__global__ void count_edges(const int* __restrict__ dst, int* __restrict__ counts) {
    const int i = blockIdx.x * blockDim.x + threadIdx.x;
    if (i < TOTAL_E) atomicAdd(&counts[dst[i]], 1);
}

__global__ void scan_offsets(const int* __restrict__ counts, int* __restrict__ offsets) {
    __shared__ int partials[256];
    const int tid = threadIdx.x;
    const int CH = (N_NODES + 255) / 256;  // 79
    const int base = tid * CH;

    int lsum = 0;
    for (int i = 0; i < CH; ++i) {
        int idx = base + i;
        if (idx < N_NODES) lsum += counts[idx];
    }
    partials[tid] = lsum;
    __syncthreads();
    for (int d = 1; d < 256; d <<= 1) {
        int v = (tid >= d) ? partials[tid - d] : 0;
        __syncthreads();
        partials[tid] += v;
        __syncthreads();
    }
    int run = (tid == 0) ? 0 : partials[tid - 1];
    for (int i = 0; i < CH; ++i) {
        int idx = base + i;
        if (idx < N_NODES) {
            offsets[idx] = run;
            run += counts[idx];
        }
    }
    if (tid == 255) offsets[N_NODES] = run;
}

__global__ void fill_edges(const int* __restrict__ src, const int* __restrict__ dst,
                           const float* __restrict__ w, const int* __restrict__ offsets,
                           int* __restrict__ cursor, int2* __restrict__ epack) {
    const int i = blockIdx.x * blockDim.x + threadIdx.x;
    if (i >= TOTAL_E) return;
    const int d = dst[i];
    const int pos = offsets[d] + atomicAdd(&cursor[d], 1);
    const int s = i / N_EDGES;
    int2 kp;
    kp.x = s * N_NODES + src[i];
    kp.y = __float_as_int(w[i]);
    epack[pos] = kp;
}

// ---------------- gather: one wave per node; two 32-lane halves, 4 rows in flight each ----------------
__global__ void gather_out(const unsigned short* __restrict__ yb, const int* __restrict__ offsets,
                           const int2* __restrict__ epack, float* __restrict__ out) {
    const int wid = (int)((blockIdx.x * (size_t)blockDim.x + threadIdx.x) >> 6);
    const int lane = threadIdx.x & 63;
    if (wid >= N_NODES) return;
    const int half = lane >> 5;     // 0: even edges, 1: odd edges
    const int l32 = lane & 31;      // covers permuted positions p = l32*8 .. l32*8+7

    const int e0 = offsets[wid];
    const int e1 = offsets[wid + 1];

    float acc[8];
#pragma unroll
    for (int j = 0; j < 8; ++j) acc[j] = 0.f;

    int e = e0 + half;
    // main loop: 4 independent row loads in flight per 32-lane half
    for (; e + 6 < e1; e += 8) {
        const int2 k1 = epack[e];
        const int2 k2 = epack[e + 2];
        const int2 k3 = epack[e + 4];
        const int2 k4 = epack[e + 6];
        ushort8 v1 = ((const ushort8*)(yb + (size_t)k1.x * OUT_DIM))[l32];
        ushort8 v2 = ((const ushort8*)(yb + (size_t)k2.x * OUT_DIM))[l32];
        ushort8 v3 = ((const ushort8*)(yb + (size_t)k3.x * OUT_DIM))[l32];
        ushort8 v4 = ((const ushort8*)(yb + (size_t)k4.x * OUT_DIM))[l32];
        const float w1 = __int_as_float(k1.y);
        const float w2 = __int_as_float(k2.y);
        const float w3 = __int_as_float(k3.y);
        const float w4 = __int_as_float(k4.y);
#pragma unroll
        for (int j = 0; j < 8; ++j) acc[j] += w1 * bf2f(v1[j]);
#pragma unroll
        for (int j = 0; j < 8; ++j) acc[j] += w2 * bf2f(v2[j]);
#pragma unroll
        for (int j = 0; j < 8; ++j) acc[j] += w3 * bf2f(v3[j]);
#pragma unroll
        for (int j = 0; j < 8; ++j) acc[j] += w4 * bf2f(v4[j]);
    }
    for (; e < e1; e += 2) {
        const int2 k1 = epack[e];
        ushort8 v1 = ((const ushort8*)(yb + (size_t)k1.x * OUT_DIM))[l32];
        const float w1 = __int_as_float(k1.y);
#pragma unroll
        for (int j = 0; j < 8; ++j) acc[j] += w1 * bf2f(v1[j]);
    }

    // combine halves
#pragma unroll
    for (int j = 0; j < 8; ++j) acc[j] += __shfl_xor(acc[j], 32, 64);

    // un-permute and store: position p = l32*8 + j  ->  col = ((p&15)<<4) | (p>>4)
    if (lane < 32) {
        float* op = out + (size_t)wid * OUT_DIM;
#pragma unroll
        for (int j = 0; j < 8; ++j) {
            const int p = l32 * 8 + j;
            const int c = ((p & 15) << 4) | (p >> 4);
            op[c] = acc[j];
        }
    }
}

extern "C" void kernel_launch(void* const* d_in, const int* in_sizes, int n_in,
                              void* d_out, int out_size, void* d_ws, size_t ws_size,
                              hipStream_t stream) {
    const float* x        = (const float*)d_in[0];
    const int*   edge_src = (const int*)d_in[1];
    const int*   edge_dst = (const int*)d_in[2];
    const float* edge_w   = (const float*)d_in[3];
    const float* W        = (const float*)d_in[4];
    float* out = (float*)d_out;

    char* ws = (char*)d_ws;
    unsigned short* yb   = (unsigned short*)(ws);               // 30,720,000 B
    unsigned short* xb   = (unsigned short*)(ws + 30720000);    // 10,240,000 B
    unsigned short* wt   = (unsigned short*)(ws + 40960000);    //    393,216 B
    int*   counts  = (int*)(ws + 41353216);                     //     80,000 B
    int*   cursor  = (int*)(ws + 41433216);                     //     80,000 B
    int*   offsets = (int*)(ws + 41513216);                     //     80,064 B
    int2*  epack   = (int2*)(ws + 41593280);                    //  7,680,000 B

    hipMemsetAsync(counts, 0, 160000, stream);  // counts + cursor (contiguous)

    convert_x<<<(N_NODES * D_FEAT / 4 + 255) / 256, 256, 0, stream>>>(x, xb);
    convert_w<<<N_SUPPORT * D_FEAT, 256, 0, stream>>>(W, wt);

    dim3 ggrid((M_PAIRS + 3) / 4, N_SUPPORT, 2);
    gemm_mfma<<<ggrid, 256, 0, stream>>>(xb, wt, yb);

    const int nb_e = (TOTAL_E + 255) / 256;
    count_edges<<<nb_e, 256, 0, stream>>>(edge_dst, counts);
    scan_offsets<<<1, 256, 0, stream>>>(counts, offsets);
    fill_edges<<<nb_e, 256, 0, stream>>>(edge_src, edge_dst, edge_w, offsets, cursor, epack);

    const int nb_g = (N_NODES + 3) / 4;
    gather_out<<<nb_g, 256, 0, stream>>>(yb, offsets, epack, out);
}

// Round 6
// 214.375 us; speedup vs baseline: 15.6712x; 1.2606x over previous
//
#include <hip/hip_runtime.h>

#define N_NODES 20000
#define D_FEAT 256
#define N_SUPPORT 3
#define N_EDGES 320000
#define OUT_DIM 256
#define TOTAL_E (N_SUPPORT * N_EDGES)
#define M_PAIRS 625
#define CAP 128

typedef __attribute__((ext_vector_type(8))) short short8;
typedef __attribute__((ext_vector_type(4))) float f32x4;

__device__ inline unsigned short f2bf(float f) {
    unsigned int u = __float_as_uint(f);
    u += 0x7fff + ((u >> 16) & 1);  // round-to-nearest-even
    return (unsigned short)(u >> 16);
}
__device__ inline float bf2f(unsigned short u) {
    return __uint_as_float(((unsigned int)u) << 16);
}

// x (fp32 [N][256]) -> xb (bf16 [N][256])
__global__ void convert_x(const float* __restrict__ x, unsigned short* __restrict__ xb) {
    int i = blockIdx.x * blockDim.x + threadIdx.x;
    if ((size_t)i * 4 >= (size_t)N_NODES * D_FEAT) return;
    float4 v = ((const float4*)x)[i];
    ushort4 o;
    o.x = f2bf(v.x); o.y = f2bf(v.y); o.z = f2bf(v.z); o.w = f2bf(v.w);
    ((ushort4*)xb)[i] = o;
}

// W (fp32 [S*256][256]) -> wt (bf16 [S][n=256][k=256]) transposed
__global__ void convert_w(const float* __restrict__ W, unsigned short* __restrict__ wt) {
    const int row = blockIdx.x;      // s*256 + k
    const int n = threadIdx.x;
    const int s = row >> 8;
    const int k = row & 255;
    float v = W[(size_t)row * OUT_DIM + n];
    wt[((size_t)s * OUT_DIM + n) * D_FEAT + k] = f2bf(v);
}

// y_s = x @ W_s via MFMA; yb NORMAL layout [s][node][col] bf16.
// Each wave: 2 M-tiles (32 rows) x 8 N-tiles (128 cols). grid (157,3,2), block 256.
__global__ void __launch_bounds__(256) gemm_mfma(const unsigned short* __restrict__ xb,
                                                 const unsigned short* __restrict__ wt,
                                                 unsigned short* __restrict__ yb) {
    const int s = blockIdx.y;
    const int nh = blockIdx.z;
    const int wid = threadIdx.x >> 6;
    const int lane = threadIdx.x & 63;
    const int pair = blockIdx.x * 4 + wid;
    if (pair >= M_PAIRS) return;
    const int r0 = pair * 32;
    const int cit = lane & 15;
    const int kgrp = (lane >> 4) * 8;

    const short* a0p = (const short*)xb + (size_t)(r0 + cit) * D_FEAT + kgrp;
    const short* a1p = a0p + (size_t)16 * D_FEAT;
    const short* bp  = (const short*)wt + (size_t)s * D_FEAT * OUT_DIM
                     + (size_t)(nh * 8) * 16 * D_FEAT + (size_t)cit * D_FEAT + kgrp;

    f32x4 acc0[8], acc1[8];
#pragma unroll
    for (int nt = 0; nt < 8; ++nt) {
        acc0[nt] = (f32x4){0.f, 0.f, 0.f, 0.f};
        acc1[nt] = (f32x4){0.f, 0.f, 0.f, 0.f};
    }

#pragma unroll
    for (int kk = 0; kk < 8; ++kk) {
        short8 a0 = *(const short8*)(a0p + kk * 32);
        short8 a1 = *(const short8*)(a1p + kk * 32);
#pragma unroll
        for (int nt = 0; nt < 8; ++nt) {
            short8 b = *(const short8*)(bp + (size_t)nt * 16 * D_FEAT + kk * 32);
            acc0[nt] = __builtin_amdgcn_mfma_f32_16x16x32_bf16(a0, b, acc0[nt], 0, 0, 0);
            acc1[nt] = __builtin_amdgcn_mfma_f32_16x16x32_bf16(a1, b, acc1[nt], 0, 0, 0);
        }
    }

    // normal-layout store: row rbase+r, col = (nh*8+j)*16 + cit  (round-2-verified mapping)
    unsigned short* yp = (unsigned short*)yb + ((size_t)s * N_NODES + r0) * OUT_DIM;
    const int rbase = (lane >> 4) * 4;
#pragma unroll
    for (int r = 0; r < 4; ++r) {
        unsigned short* row0 = yp + (size_t)(rbase + r) * OUT_DIM;
        unsigned short* row1 = row0 + (size_t)16 * OUT_DIM;
#pragma unroll
        for (int j = 0; j < 8; ++j) {
            const int col = (nh * 8 + j) * 16 + cit;
            row0[col] = f2bf(acc0[j][r]);
            row1[col] = f2bf(acc1[j][r]);
        }
    }
}

// ---------------- bucket fill: padded CSR, CAP entries/node, 4B records ----------------
__global__ void fill_edges(const int* __restrict__ src, const int* __restrict__ dst,
                           const float* __restrict__ w, int* __restrict__ cursor,
                           unsigned int* __restrict__ epack) {
    const int i = blockIdx.x * blockDim.x + threadIdx.x;
    if (i >= TOTAL_E) return;
    const int d = dst[i];
    const int pos = atomicAdd(&cursor[d], 1);
    if (pos >= CAP) return;  // statistically unreachable (max deg ~79)
    const int s = i / N_EDGES;
    const unsigned int key = (unsigned int)(s * N_NODES + src[i]);
    const unsigned int w16 = f2bf(w[i]);
    epack[(size_t)d * CAP + pos] = key | (w16 << 16);
}

// ---------------- gather: XCD-local column chunks ----------------
// chunk = blockIdx.x & 7 (round-robins over the 8 XCDs) -> each XCD's working set
// is yb[:, chunk*32 : chunk*32+32] = 3.84 MB, fits its private 4 MB L2.
// Per wave: one node, one chunk. 8 lanes per edge (8 B each), 8 edges/iter.
__global__ void __launch_bounds__(256) gather_out(const unsigned short* __restrict__ yb,
                                                  const int* __restrict__ cursor,
                                                  const unsigned int* __restrict__ epack,
                                                  float* __restrict__ out) {
    const int c = blockIdx.x & 7;
    const int node = (blockIdx.x >> 3) * 4 + (threadIdx.x >> 6);
    const int lane = threadIdx.x & 63;
    const int eg = lane >> 3;   // 0..7 edge group
    const int cl = lane & 7;    // 0..7 col sub-index (4 cols each)

    int cnt = cursor[node];
    if (cnt > CAP) cnt = CAP;
    const unsigned int* ep = epack + (size_t)node * CAP;
    const unsigned short* ybase = yb + c * 32 + cl * 4;

    float a0 = 0.f, a1 = 0.f, a2 = 0.f, a3 = 0.f;

    int it = eg;
    for (; it + 8 < cnt; it += 16) {
        const unsigned int pk1 = ep[it];
        const unsigned int pk2 = ep[it + 8];
        ushort4 v1 = *(const ushort4*)(ybase + (size_t)(pk1 & 0xFFFFu) * OUT_DIM);
        ushort4 v2 = *(const ushort4*)(ybase + (size_t)(pk2 & 0xFFFFu) * OUT_DIM);
        const float w1 = __uint_as_float(pk1 & 0xFFFF0000u);
        const float w2 = __uint_as_float(pk2 & 0xFFFF0000u);
        a0 += w1 * bf2f(v1.x) + w2 * bf2f(v2.x);
        a1 += w1 * bf2f(v1.y) + w2 * bf2f(v2.y);
        a2 += w1 * bf2f(v1.z) + w2 * bf2f(v2.z);
        a3 += w1 * bf2f(v1.w) + w2 * bf2f(v2.w);
    }
    if (it < cnt) {
        const unsigned int pk1 = ep[it];
        ushort4 v1 = *(const ushort4*)(ybase + (size_t)(pk1 & 0xFFFFu) * OUT_DIM);
        const float w1 = __uint_as_float(pk1 & 0xFFFF0000u);
        a0 += w1 * bf2f(v1.x);
        a1 += w1 * bf2f(v1.y);
        a2 += w1 * bf2f(v1.z);
        a3 += w1 * bf2f(v1.w);
    }

    // reduce across the 8 edge groups (lanes differing in bits 3..5)
#pragma unroll
    for (int m = 8; m <= 32; m <<= 1) {
        a0 += __shfl_xor(a0, m, 64);
        a1 += __shfl_xor(a1, m, 64);
        a2 += __shfl_xor(a2, m, 64);
        a3 += __shfl_xor(a3, m, 64);
    }

    if (lane < 8) {
        float4 o = {a0, a1, a2, a3};
        *(float4*)(out + (size_t)node * OUT_DIM + c * 32 + lane * 4) = o;
    }
}

extern "C" void kernel_launch(void* const* d_in, const int* in_sizes, int n_in,
                              void* d_out, int out_size, void* d_ws, size_t ws_size,
                              hipStream_t stream) {
    const float* x        = (const float*)d_in[0];
    const int*   edge_src = (const int*)d_in[1];
    const int*   edge_dst = (const int*)d_in[2];
    const float* edge_w   = (const float*)d_in[3];
    const float* W        = (const float*)d_in[4];
    float* out = (float*)d_out;

    char* ws = (char*)d_ws;
    unsigned short* yb     = (unsigned short*)(ws);              // 30,720,000 B
    unsigned short* xb     = (unsigned short*)(ws + 30720000);   // 10,240,000 B
    unsigned short* wt     = (unsigned short*)(ws + 40960000);   //    393,216 B
    int*            cursor = (int*)(ws + 41353216);              //     80,000 B
    unsigned int*   epack  = (unsigned int*)(ws + 41433216);     // 10,240,000 B
    // total: 51,673,216 B

    hipMemsetAsync(cursor, 0, 80000, stream);

    convert_x<<<(N_NODES * D_FEAT / 4 + 255) / 256, 256, 0, stream>>>(x, xb);
    convert_w<<<N_SUPPORT * D_FEAT, 256, 0, stream>>>(W, wt);

    dim3 ggrid((M_PAIRS + 3) / 4, N_SUPPORT, 2);
    gemm_mfma<<<ggrid, 256, 0, stream>>>(xb, wt, yb);

    fill_edges<<<(TOTAL_E + 255) / 256, 256, 0, stream>>>(edge_src, edge_dst, edge_w, cursor, epack);

    // 8 chunks x 5000 node-groups (4 nodes/block)
    gather_out<<<8 * (N_NODES / 4), 256, 0, stream>>>(yb, cursor, epack, out);
}

// Round 7
// 196.765 us; speedup vs baseline: 17.0737x; 1.0895x over previous
//
#include <hip/hip_runtime.h>

#define N_NODES 20000
#define D_FEAT 256
#define N_SUPPORT 3
#define N_EDGES 320000
#define OUT_DIM 256
#define TOTAL_E (N_SUPPORT * N_EDGES)
#define CAP 64                      // per-(s,dst) bucket; mean deg 16, P(>64) ~ 1e-9
#define KDIM (N_SUPPORT * D_FEAT)   // 768
#define HPAD (KDIM + 8)             // 776: LDS row stride; stride 1552B -> 2-way bank (free)

typedef __attribute__((ext_vector_type(8))) short short8;
typedef __attribute__((ext_vector_type(8))) unsigned short ushort8;
typedef __attribute__((ext_vector_type(4))) float f32x4;

__device__ inline unsigned short f2bf(float f) {
    unsigned int u = __float_as_uint(f);
    u += 0x7fff + ((u >> 16) & 1);  // round-to-nearest-even
    return (unsigned short)(u >> 16);
}
__device__ inline float bf2f(unsigned short u) {
    return __uint_as_float(((unsigned int)u) << 16);
}

// x (fp32 [N][256]) -> xb (bf16 [N][256])
__global__ void convert_x(const float* __restrict__ x, unsigned short* __restrict__ xb) {
    int i = blockIdx.x * blockDim.x + threadIdx.x;
    if ((size_t)i * 4 >= (size_t)N_NODES * D_FEAT) return;
    float4 v = ((const float4*)x)[i];
    ushort4 o;
    o.x = f2bf(v.x); o.y = f2bf(v.y); o.z = f2bf(v.z); o.w = f2bf(v.w);
    ((ushort4*)xb)[i] = o;
}

// W (fp32 [S*256][256]) -> wt (bf16 [S][n=256][k=256]) transposed
__global__ void convert_w(const float* __restrict__ W, unsigned short* __restrict__ wt) {
    const int row = blockIdx.x;      // s*256 + k
    const int n = threadIdx.x;
    const int s = row >> 8;
    const int k = row & 255;
    float v = W[(size_t)row * OUT_DIM + n];
    wt[((size_t)s * OUT_DIM + n) * D_FEAT + k] = f2bf(v);
}

// padded per-(s,dst) buckets, 4B records: src | (w_bf16 << 16)
__global__ void fill_edges(const int* __restrict__ src, const int* __restrict__ dst,
                           const float* __restrict__ w, int* __restrict__ cursor,
                           unsigned int* __restrict__ epack) {
    const int i = blockIdx.x * blockDim.x + threadIdx.x;
    if (i >= TOTAL_E) return;
    const int s = i / N_EDGES;
    const int b = s * N_NODES + dst[i];
    const int pos = atomicAdd(&cursor[b], 1);
    if (pos >= CAP) return;  // statistically unreachable
    epack[(size_t)b * CAP + pos] = (unsigned int)src[i] | (((unsigned int)f2bf(w[i])) << 16);
}

// Fused: per 32-node dst tile, gather-accumulate h=[32][768] (bf16, in LDS),
// then out_tile = h @ W via MFMA. One block = 8 waves = 512 threads.
// Phase 1: wave handles 4 nodes x 3 supports; 32-lane halves process alternate
//          edges, each lane covers 8 cols (16B x-row slice), MLP2.
// Phase 2: wave (m = wid&1, ntg = wid>>1) computes 16x64 of the 32x256 out tile.
__global__ void __launch_bounds__(512) fused_gather_gemm(
        const unsigned short* __restrict__ xb, const unsigned short* __restrict__ wt,
        const int* __restrict__ cursor, const unsigned int* __restrict__ epack,
        float* __restrict__ out) {
    __shared__ unsigned short h[32][HPAD];   // 49,664 B
    const int n0 = blockIdx.x * 32;
    const int wid = threadIdx.x >> 6;
    const int lane = threadIdx.x & 63;
    const int half = lane >> 5;
    const int l32 = lane & 31;

    // ---- phase 1: gather-aggregate ----
    for (int ni = 0; ni < 4; ++ni) {
        const int lr = wid * 4 + ni;         // local dst row 0..31
        const int node = n0 + lr;
        for (int s = 0; s < N_SUPPORT; ++s) {
            const int b = s * N_NODES + node;
            int cnt = cursor[b]; if (cnt > CAP) cnt = CAP;
            const unsigned int* ep = epack + (size_t)b * CAP;
            float a[8];
#pragma unroll
            for (int j = 0; j < 8; ++j) a[j] = 0.f;
            int it = half;
            for (; it + 2 < cnt; it += 4) {   // 2 rows in flight per half
                const unsigned int p1 = ep[it];
                const unsigned int p2 = ep[it + 2];
                ushort8 v1 = *(const ushort8*)(xb + (size_t)(p1 & 0xFFFFu) * D_FEAT + l32 * 8);
                ushort8 v2 = *(const ushort8*)(xb + (size_t)(p2 & 0xFFFFu) * D_FEAT + l32 * 8);
                const float w1 = __uint_as_float(p1 & 0xFFFF0000u);
                const float w2 = __uint_as_float(p2 & 0xFFFF0000u);
#pragma unroll
                for (int j = 0; j < 8; ++j) a[j] += w1 * bf2f(v1[j]) + w2 * bf2f(v2[j]);
            }
            if (it < cnt) {
                const unsigned int p1 = ep[it];
                ushort8 v1 = *(const ushort8*)(xb + (size_t)(p1 & 0xFFFFu) * D_FEAT + l32 * 8);
                const float w1 = __uint_as_float(p1 & 0xFFFF0000u);
#pragma unroll
                for (int j = 0; j < 8; ++j) a[j] += w1 * bf2f(v1[j]);
            }
            // combine the two halves
#pragma unroll
            for (int j = 0; j < 8; ++j) a[j] += __shfl_xor(a[j], 32, 64);
            if (half == 0) {
                ushort8 o;
#pragma unroll
                for (int j = 0; j < 8; ++j) o[j] = f2bf(a[j]);
                *(ushort8*)&h[lr][s * D_FEAT + l32 * 8] = o;
            }
        }
    }
    __syncthreads();

    // ---- phase 2: out tile = h @ W ----
    const int m = wid & 1;
    const int ntg = wid >> 1;            // n-tiles ntg*4 .. ntg*4+3
    const int cit = lane & 15;
    const int kgrp = (lane >> 4) * 8;
    const int arow = m * 16 + cit;

    f32x4 acc[4];
#pragma unroll
    for (int j = 0; j < 4; ++j) acc[j] = (f32x4){0.f, 0.f, 0.f, 0.f};

#pragma unroll
    for (int kk = 0; kk < KDIM / 32; ++kk) {   // 24 k-steps
        const int k0 = kk * 32;
        short8 av = *(const short8*)&h[arow][k0 + kgrp];
        const int s = k0 >> 8;
        const int kp = (k0 & 255) + kgrp;
        const short* bbase = (const short*)wt + (size_t)s * D_FEAT * OUT_DIM
                           + (size_t)cit * D_FEAT + kp;
#pragma unroll
        for (int j = 0; j < 4; ++j) {
            const int nt = ntg * 4 + j;
            short8 bv = *(const short8*)(bbase + (size_t)nt * 16 * D_FEAT);
            acc[j] = __builtin_amdgcn_mfma_f32_16x16x32_bf16(av, bv, acc[j], 0, 0, 0);
        }
    }

    // C-write (round-2-verified mapping): row = rbase+r, col = nt*16 + cit
    const int rbase = (lane >> 4) * 4;
#pragma unroll
    for (int j = 0; j < 4; ++j) {
        const int col = (ntg * 4 + j) * 16 + cit;
#pragma unroll
        for (int r = 0; r < 4; ++r) {
            out[(size_t)(n0 + m * 16 + rbase + r) * OUT_DIM + col] = acc[j][r];
        }
    }
}

extern "C" void kernel_launch(void* const* d_in, const int* in_sizes, int n_in,
                              void* d_out, int out_size, void* d_ws, size_t ws_size,
                              hipStream_t stream) {
    const float* x        = (const float*)d_in[0];
    const int*   edge_src = (const int*)d_in[1];
    const int*   edge_dst = (const int*)d_in[2];
    const float* edge_w   = (const float*)d_in[3];
    const float* W        = (const float*)d_in[4];
    float* out = (float*)d_out;

    char* ws = (char*)d_ws;
    unsigned short* xb     = (unsigned short*)(ws);              // 10,240,000 B
    unsigned short* wt     = (unsigned short*)(ws + 10240000);   //    393,216 B
    int*            cursor = (int*)(ws + 10633216);              //    240,000 B
    unsigned int*   epack  = (unsigned int*)(ws + 10873216);     // 15,360,000 B
    // total: 26,233,216 B

    hipMemsetAsync(cursor, 0, 240000, stream);

    convert_x<<<(N_NODES * D_FEAT / 4 + 255) / 256, 256, 0, stream>>>(x, xb);
    convert_w<<<N_SUPPORT * D_FEAT, 256, 0, stream>>>(W, wt);

    fill_edges<<<(TOTAL_E + 255) / 256, 256, 0, stream>>>(edge_src, edge_dst, edge_w, cursor, epack);

    fused_gather_gemm<<<N_NODES / 32, 512, 0, stream>>>(xb, wt, cursor, epack, out);
}